// Round 14
// baseline (3812.177 us; speedup 1.0000x reference)
//
#include <hip/hip_runtime.h>

#define SEQ_T 2048
#define BATCH 64

typedef _Float16 half2v __attribute__((ext_vector_type(2)));

#if defined(__has_builtin)
#  if __has_builtin(__builtin_amdgcn_fdot2)
#    define HAVE_FDOT2 1
#  endif
#endif

// f16-pair dot with f32 accumulate — builtin or exact-f32 fallback.
// NOTE: inline-asm v_dot2_f32_f16 correlated with ~0.1 absmax (R4/R5) — banned.
__device__ __forceinline__ float fdot2f(half2v a, half2v b, float c) {
#ifdef HAVE_FDOT2
  return __builtin_amdgcn_fdot2(a, b, c, false);
#else
  return c + (float)a[0] * (float)b[0] + (float)a[1] * (float)b[1];
#endif
}

__device__ __forceinline__ unsigned int h2u(half2v v) { return __builtin_bit_cast(unsigned int, v); }
__device__ __forceinline__ half2v u2h(unsigned int u) { return __builtin_bit_cast(half2v, u); }

// Single-instruction mixed f16xf32 MAC with f32 accumulator.
// Semantics == fmaf((float)w.half, h, acc): exact f16->f32 conversion + one
// IEEE f32 FMA (verified: absmax identical to the cvt+fma path in R13).
__device__ __forceinline__ float fma_mix_lo(float acc, half2v w, float h) {
  asm("v_fma_mix_f32 %0, %1, %2, %0 op_sel_hi:[1,0,0]"
      : "+v"(acc) : "v"(w), "v"(h));
  return acc;
}
__device__ __forceinline__ float fma_mix_hi(float acc, half2v w, float h) {
  asm("v_fma_mix_f32 %0, %1, %2, %0 op_sel:[1,0,0] op_sel_hi:[1,0,0]"
      : "+v"(acc) : "v"(w), "v"(h));
  return acc;
}

// Within-quad lane permute on the VALU (DPP quad_perm) — no LDS pipe.
template <int CTRL>
__device__ __forceinline__ float qperm(float x) {
  int xi = __builtin_bit_cast(int, x);
  int ri = __builtin_amdgcn_update_dpp(xi, xi, CTRL, 0xF, 0xF, true);
  return __builtin_bit_cast(float, ri);
}
#define QP_XOR1 0xB1  // [1,0,3,2]
#define QP_XOR2 0x4E  // [2,3,0,1]
#define QP_B0   0x00
#define QP_B1   0x55
#define QP_B2   0xAA
#define QP_B3   0xFF

// ---------------------------------------------------------------------------
// xproj GEMM (R2/R3-proven, unchanged): xp[tb][r*4+g] gate-interleaved f16.
// ---------------------------------------------------------------------------
template <int K, bool IN_F32>
__global__ __launch_bounds__(512) void xproj_gemm(
    const void* __restrict__ Xv,            // [M][K] f32 or f16
    const float* __restrict__ W,            // [512][K] f32
    const float* __restrict__ bih, const float* __restrict__ bhh,
    unsigned short* __restrict__ xp)        // [M][512] f16, gate-interleaved
{
  constexpr int MT = 64;
  const int g = threadIdx.x;
  const size_t m0 = (size_t)blockIdx.x * MT;

  __shared__ __align__(16) _Float16 xs[MT * K];

  if constexpr (IN_F32) {
    constexpr int PER = MT * K / 512;
    const float* Xf = (const float*)Xv + m0 * K + (size_t)g * PER;
    _Float16* dst = xs + g * PER;
#pragma unroll
    for (int i = 0; i < PER; i += 4) {
      float4 v = *reinterpret_cast<const float4*>(Xf + i);
      half2v h01; h01[0] = (_Float16)v.x; h01[1] = (_Float16)v.y;
      half2v h23; h23[0] = (_Float16)v.z; h23[1] = (_Float16)v.w;
      uint2 u; u.x = h2u(h01); u.y = h2u(h23);
      *reinterpret_cast<uint2*>(dst + i) = u;
    }
  } else {
    constexpr int PER = MT * K / 512;
    const unsigned short* Xh = (const unsigned short*)Xv + m0 * K + (size_t)g * PER;
#pragma unroll
    for (int i = 0; i < PER / 8; i++)
      reinterpret_cast<uint4*>(xs + g * PER)[i] = reinterpret_cast<const uint4*>(Xh)[i];
  }

  half2v wr[K / 2];
  {
    const float2* p = reinterpret_cast<const float2*>(W + (size_t)g * K);
#pragma unroll
    for (int k = 0; k < K / 2; k++) {
      float2 f = p[k];
      half2v v; v[0] = (_Float16)f.x; v[1] = (_Float16)f.y;
      wr[k] = v;
    }
  }
  const float bias = bih[g] + bhh[g];
  const int out_off = (g & 127) * 4 + (g >> 7);
  __syncthreads();

#pragma unroll 1
  for (int tb = 0; tb < MT; tb++) {
    const uint4* xv = reinterpret_cast<const uint4*>(xs + tb * K);
    float a0 = bias, a1 = 0.f, a2 = 0.f, a3 = 0.f;
#pragma unroll
    for (int i = 0; i < K / 8; i++) {
      const uint4 u = xv[i];
      a0 = fdot2f(wr[4 * i + 0], u2h(u.x), a0);
      a1 = fdot2f(wr[4 * i + 1], u2h(u.y), a1);
      a2 = fdot2f(wr[4 * i + 2], u2h(u.z), a2);
      a3 = fdot2f(wr[4 * i + 3], u2h(u.w), a3);
    }
    const float s = (a0 + a1) + (a2 + a3);
    xp[(m0 + tb) * 512 + out_off] = __builtin_bit_cast(unsigned short, (_Float16)s);
  }
}

// ---------------------------------------------------------------------------
// Recurrence R14 = R13 with the asm MAC stream ROUND-ROBINED across the four
// accumulator chains (a0,a1,a2,a3 per h-element). R13 grouped 4 dependent
// FMAs per chain back-to-back; LLVM keeps asm source order, so each chain
// stalled ~2cyc/instr on the 4-cyc FMA latency. Round-robin spaces each
// accumulator's uses >=8 cyc apart — latency fully hidden.
// thread = (row r = wave*16 + (l>>2), K-split ks = l&3).
// ---------------------------------------------------------------------------
struct StepCtx {
  int ks, r, hidx;
  float sc, am, ab;
  bool writer;
};

__device__ __forceinline__ float sigmoid_fast(float x) {
  return 1.f / (1.f + __expf(-x));
}

__device__ __forceinline__ void lstm_step(
    int cur, const StepCtx& cx,
    const half2v (&wh)[4][16], float (&hbuf)[2][144],
    unsigned short& pf, const unsigned short*& pf_ptr,
    float& c, unsigned short*& hout_ptr)
{
  // consume 2-steps-ago prefetch; immediately re-issue 2 ahead
  const float xpv = (float)__builtin_bit_cast(_Float16, pf);
  pf = *pf_ptr;
  pf_ptr += 2 * BATCH * 512;

  float a0 = 0.f, a1 = 0.f, a2 = 0.f, a3 = 0.f;
  const float4* hv = reinterpret_cast<const float4*>(&hbuf[cur][cx.ks * 36]);
#pragma unroll
  for (int i = 0; i < 8; i++) {
    const float4 u = hv[i];
    const half2v w0a = wh[0][2 * i], w0b = wh[0][2 * i + 1];
    const half2v w1a = wh[1][2 * i], w1b = wh[1][2 * i + 1];
    const half2v w2a = wh[2][2 * i], w2b = wh[2][2 * i + 1];
    const half2v w3a = wh[3][2 * i], w3b = wh[3][2 * i + 1];
    // round-robin: each accumulator touched every 4 instructions
    a0 = fma_mix_lo(a0, w0a, u.x);
    a1 = fma_mix_lo(a1, w1a, u.x);
    a2 = fma_mix_lo(a2, w2a, u.x);
    a3 = fma_mix_lo(a3, w3a, u.x);
    a0 = fma_mix_hi(a0, w0a, u.y);
    a1 = fma_mix_hi(a1, w1a, u.y);
    a2 = fma_mix_hi(a2, w2a, u.y);
    a3 = fma_mix_hi(a3, w3a, u.y);
    a0 = fma_mix_lo(a0, w0b, u.z);
    a1 = fma_mix_lo(a1, w1b, u.z);
    a2 = fma_mix_lo(a2, w2b, u.z);
    a3 = fma_mix_lo(a3, w3b, u.z);
    a0 = fma_mix_hi(a0, w0b, u.w);
    a1 = fma_mix_hi(a1, w1b, u.w);
    a2 = fma_mix_hi(a2, w2b, u.w);
    a3 = fma_mix_hi(a3, w3b, u.w);
  }

  // quad reduce-scatter via DPP: lane ks ends with the full sum of gate ks
  const bool q0 = (cx.ks & 1) != 0, q1 = (cx.ks & 2) != 0;
  float s0 = q0 ? a0 : a1;
  float s1 = q0 ? a2 : a3;
  float r0 = qperm<QP_XOR1>(s0);
  float r1 = qperm<QP_XOR1>(s1);
  float kA = (q0 ? a1 : a0) + r0;
  float kB = (q0 ? a3 : a2) + r1;
  float s2 = q1 ? kA : kB;
  float r2 = qperm<QP_XOR2>(s2);
  float sum = (q1 ? kB : kA) + r2 + xpv;

  // ONE activation per lane: y = am * sigmoid(sc*sum) + ab
  float y = cx.am * sigmoid_fast(cx.sc * sum) + cx.ab;

  // all-gather activated gates across the quad via DPP broadcasts
  float gi = qperm<QP_B0>(y);
  float gf = qperm<QP_B1>(y);
  float gg = qperm<QP_B2>(y);
  float go = qperm<QP_B3>(y);

  c = gf * c + gi * gg;
  float th = 2.f * sigmoid_fast(2.f * c) - 1.f;
  float h = go * th;

  if (cx.writer) {
    hbuf[cur ^ 1][cx.hidx] = h;
    *hout_ptr = __builtin_bit_cast(unsigned short, (_Float16)h);
  }
  hout_ptr += BATCH * 128;

  __syncthreads();
}

__global__ __launch_bounds__(512)
__attribute__((amdgpu_waves_per_eu(2, 2)))
void lstm_rec2(
    const float* __restrict__ Whh,          // [512][128] f32
    const unsigned short* __restrict__ xp,  // [T*B][512] f16 gate-interleaved
    unsigned short* __restrict__ hout)      // [T*B][128] f16
{
  const int b = blockIdx.x;
  const int tid = threadIdx.x;
  const int l = tid & 63;
  const int w = tid >> 6;
  const int rr = l >> 2;
  const int ks = l & 3;
  const int r = w * 16 + rr;

  __shared__ __align__(16) float hbuf[2][144];   // 4 chunks x 36 (skewed)

  // Whh rows for this thread's 4 gates, chunk ks*32..+32, as f16 pairs (64 VGPR)
  half2v wh[4][16];
#pragma unroll
  for (int g = 0; g < 4; g++) {
    const float4* p = reinterpret_cast<const float4*>(
        Whh + ((size_t)(g * 128 + r)) * 128 + ks * 32);
#pragma unroll
    for (int k = 0; k < 8; k++) {
      float4 f = p[k];
      half2v lo; lo[0] = (_Float16)f.x; lo[1] = (_Float16)f.y;
      half2v hi; hi[0] = (_Float16)f.z; hi[1] = (_Float16)f.w;
      wh[g][2 * k] = lo;
      wh[g][2 * k + 1] = hi;
    }
  }

  StepCtx cx;
  cx.ks = ks; cx.r = r;
  cx.hidx = (r >> 5) * 36 + (r & 31);
  cx.sc = (ks == 2) ? 2.f : 1.f;
  cx.am = (ks == 2) ? 2.f : 1.f;
  cx.ab = (ks == 2) ? -1.f : 0.f;
  cx.writer = (ks == 0);

  if (tid < 144) { hbuf[0][tid] = 0.f; }

  const unsigned short* xpb = xp + (size_t)b * 512 + tid;  // tid == r*4+ks
  unsigned short pfa = xpb[0];
  unsigned short pfb = xpb[(size_t)1 * (BATCH * 512)];
  const unsigned short* pA = xpb + (size_t)2 * (BATCH * 512);
  const unsigned short* pB = xpb + (size_t)3 * (BATCH * 512);
  unsigned short* houtp = hout + (size_t)b * 128 + r;
  float c = 0.f;
  __syncthreads();

#pragma unroll 1
  for (int t = 0; t < SEQ_T; t += 2) {
    lstm_step(0, cx, wh, hbuf, pfa, pA, c, houtp);
    lstm_step(1, cx, wh, hbuf, pfb, pB, c, houtp);
  }
}

// ---------------------------------------------------------------------------
// Final linear: out[tb] = h1[tb]·wlin + blin  (R3-proven)
// ---------------------------------------------------------------------------
__global__ __launch_bounds__(256) void final_lin(
    const unsigned short* __restrict__ h1,  // [T*B][128] f16
    const float* __restrict__ Wlin, const float* __restrict__ blin,
    float* __restrict__ out)
{
  const size_t tb = (size_t)blockIdx.x * 256 + threadIdx.x;
  half2v wl[64];
  const float2* p = reinterpret_cast<const float2*>(Wlin);
#pragma unroll
  for (int k = 0; k < 64; k++) {
    float2 f = p[k];
    half2v v; v[0] = (_Float16)f.x; v[1] = (_Float16)f.y;
    wl[k] = v;
  }
  const uint4* hv = reinterpret_cast<const uint4*>(h1 + tb * 128);
  float a0 = 0.f, a1 = 0.f, a2 = 0.f, a3 = 0.f;
#pragma unroll
  for (int i = 0; i < 16; i++) {
    const uint4 u = hv[i];
    a0 = fdot2f(wl[4 * i + 0], u2h(u.x), a0);
    a1 = fdot2f(wl[4 * i + 1], u2h(u.y), a1);
    a2 = fdot2f(wl[4 * i + 2], u2h(u.z), a2);
    a3 = fdot2f(wl[4 * i + 3], u2h(u.w), a3);
  }
  out[tb] = (a0 + a1) + (a2 + a3) + blin[0];
}

extern "C" void kernel_launch(void* const* d_in, const int* in_sizes, int n_in,
                              void* d_out, int out_size, void* d_ws, size_t ws_size,
                              hipStream_t stream) {
  (void)in_sizes; (void)n_in; (void)out_size; (void)ws_size;

  const float* data = (const float*)d_in[0];
  const float* Wih0 = (const float*)d_in[1];
  const float* Whh0 = (const float*)d_in[2];
  const float* bih0 = (const float*)d_in[3];
  const float* bhh0 = (const float*)d_in[4];
  const float* Wih1 = (const float*)d_in[5];
  const float* Whh1 = (const float*)d_in[6];
  const float* bih1 = (const float*)d_in[7];
  const float* bhh1 = (const float*)d_in[8];
  const float* Wlin = (const float*)d_in[9];
  const float* blin = (const float*)d_in[10];

  // ws layout: xp 128 MiB | h0 32 MiB | h1 32 MiB
  unsigned char* ws = (unsigned char*)d_ws;
  unsigned short* xpb = (unsigned short*)ws;
  unsigned short* h0 = (unsigned short*)(ws + (size_t)128 * 1024 * 1024);
  unsigned short* h1 = (unsigned short*)(ws + (size_t)160 * 1024 * 1024);

  const int M = SEQ_T * BATCH;
  const int gemm_blocks = M / 64;

  xproj_gemm<64, true><<<dim3(gemm_blocks), dim3(512), 0, stream>>>(
      data, Wih0, bih0, bhh0, xpb);
  lstm_rec2<<<dim3(BATCH), dim3(512), 0, stream>>>(Whh0, xpb, h0);
  xproj_gemm<128, false><<<dim3(gemm_blocks), dim3(512), 0, stream>>>(
      h0, Wih1, bih1, bhh1, xpb);
  lstm_rec2<<<dim3(BATCH), dim3(512), 0, stream>>>(Whh1, xpb, h1);
  final_lin<<<dim3(M / 256), dim3(256), 0, stream>>>(h1, Wlin, blin, (float*)d_out);
}

// Round 15
// 3208.141 us; speedup vs baseline: 1.1883x; 1.1883x over previous
//
#include <hip/hip_runtime.h>

#define SEQ_T 2048
#define BATCH 64

typedef _Float16 half2v __attribute__((ext_vector_type(2)));

#if defined(__has_builtin)
#  if __has_builtin(__builtin_amdgcn_fdot2)
#    define HAVE_FDOT2 1
#  endif
#endif

// f16-pair dot with f32 accumulate — builtin or exact-f32 fallback.
// NOTE: inline-asm v_dot2_f32_f16 correlated with ~0.1 absmax (R4/R5) — banned.
// NOTE: inline-asm v_fma_mix_f32 was a NULL/regression (R13/R14) — banned.
__device__ __forceinline__ float fdot2f(half2v a, half2v b, float c) {
#ifdef HAVE_FDOT2
  return __builtin_amdgcn_fdot2(a, b, c, false);
#else
  return c + (float)a[0] * (float)b[0] + (float)a[1] * (float)b[1];
#endif
}

// Packed f16 FMA (2 MACs / instruction): v_pk_fma_f16 via elementwise builtin.
__device__ __forceinline__ half2v pkfma(half2v a, half2v b, half2v c) {
#if __has_builtin(__builtin_elementwise_fma)
  return __builtin_elementwise_fma(a, b, c);
#else
  half2v r; r[0] = a[0] * b[0] + c[0]; r[1] = a[1] * b[1] + c[1]; return r;
#endif
}

__device__ __forceinline__ unsigned int h2u(half2v v) { return __builtin_bit_cast(unsigned int, v); }
__device__ __forceinline__ half2v u2h(unsigned int u) { return __builtin_bit_cast(half2v, u); }

// Within-quad lane permute on the VALU (DPP quad_perm) — no LDS pipe.
template <int CTRL>
__device__ __forceinline__ float qperm(float x) {
  int xi = __builtin_bit_cast(int, x);
  int ri = __builtin_amdgcn_update_dpp(xi, xi, CTRL, 0xF, 0xF, true);
  return __builtin_bit_cast(float, ri);
}
#define QP_XOR1 0xB1  // [1,0,3,2]
#define QP_XOR2 0x4E  // [2,3,0,1]
#define QP_B0   0x00
#define QP_B1   0x55
#define QP_B2   0xAA
#define QP_B3   0xFF

// ---------------------------------------------------------------------------
// xproj GEMM (R2/R3-proven, unchanged): xp[tb][r*4+g] gate-interleaved f16.
// ---------------------------------------------------------------------------
template <int K, bool IN_F32>
__global__ __launch_bounds__(512) void xproj_gemm(
    const void* __restrict__ Xv,            // [M][K] f32 or f16
    const float* __restrict__ W,            // [512][K] f32
    const float* __restrict__ bih, const float* __restrict__ bhh,
    unsigned short* __restrict__ xp)        // [M][512] f16, gate-interleaved
{
  constexpr int MT = 64;
  const int g = threadIdx.x;
  const size_t m0 = (size_t)blockIdx.x * MT;

  __shared__ __align__(16) _Float16 xs[MT * K];

  if constexpr (IN_F32) {
    constexpr int PER = MT * K / 512;
    const float* Xf = (const float*)Xv + m0 * K + (size_t)g * PER;
    _Float16* dst = xs + g * PER;
#pragma unroll
    for (int i = 0; i < PER; i += 4) {
      float4 v = *reinterpret_cast<const float4*>(Xf + i);
      half2v h01; h01[0] = (_Float16)v.x; h01[1] = (_Float16)v.y;
      half2v h23; h23[0] = (_Float16)v.z; h23[1] = (_Float16)v.w;
      uint2 u; u.x = h2u(h01); u.y = h2u(h23);
      *reinterpret_cast<uint2*>(dst + i) = u;
    }
  } else {
    constexpr int PER = MT * K / 512;
    const unsigned short* Xh = (const unsigned short*)Xv + m0 * K + (size_t)g * PER;
#pragma unroll
    for (int i = 0; i < PER / 8; i++)
      reinterpret_cast<uint4*>(xs + g * PER)[i] = reinterpret_cast<const uint4*>(Xh)[i];
  }

  half2v wr[K / 2];
  {
    const float2* p = reinterpret_cast<const float2*>(W + (size_t)g * K);
#pragma unroll
    for (int k = 0; k < K / 2; k++) {
      float2 f = p[k];
      half2v v; v[0] = (_Float16)f.x; v[1] = (_Float16)f.y;
      wr[k] = v;
    }
  }
  const float bias = bih[g] + bhh[g];
  const int out_off = (g & 127) * 4 + (g >> 7);
  __syncthreads();

#pragma unroll 1
  for (int tb = 0; tb < MT; tb++) {
    const uint4* xv = reinterpret_cast<const uint4*>(xs + tb * K);
    float a0 = bias, a1 = 0.f, a2 = 0.f, a3 = 0.f;
#pragma unroll
    for (int i = 0; i < K / 8; i++) {
      const uint4 u = xv[i];
      a0 = fdot2f(wr[4 * i + 0], u2h(u.x), a0);
      a1 = fdot2f(wr[4 * i + 1], u2h(u.y), a1);
      a2 = fdot2f(wr[4 * i + 2], u2h(u.z), a2);
      a3 = fdot2f(wr[4 * i + 3], u2h(u.w), a3);
    }
    const float s = (a0 + a1) + (a2 + a3);
    xp[(m0 + tb) * 512 + out_off] = __builtin_bit_cast(unsigned short, (_Float16)s);
  }
}

// ---------------------------------------------------------------------------
// Recurrence R15 = R9 structure with PACKED f16 dot phase:
// h stored f16 in LDS (stride-40-half chunks, 80B = 16B-aligned); weights f16
// resident (R9-proven 64-VGPR class); MACs via v_pk_fma_f16 (2 MACs/instr,
// no converts). Precision: 4 rotating half2 accumulators per gate (each f16
// slot sums only 4 products), one pk_add level, then exact f16->f32 cvts and
// f32 adds finish the gate sum. Reduce/activation/gather identical to R9.
// thread = (row r = wave*16 + (l>>2), K-split ks = l&3).
// ---------------------------------------------------------------------------
struct StepCtx {
  int ks, r, hidx;
  float sc, am, ab;
  bool writer;
};

__device__ __forceinline__ float sigmoid_fast(float x) {
  return 1.f / (1.f + __expf(-x));
}

__device__ __forceinline__ void lstm_step(
    int cur, const StepCtx& cx,
    const half2v (&wh)[4][16], _Float16 (&hbuf)[2][160],
    unsigned short& pf, const unsigned short*& pf_ptr,
    float& c, unsigned short*& hout_ptr)
{
  // consume 2-steps-ago prefetch; immediately re-issue 2 ahead
  const float xpv = (float)__builtin_bit_cast(_Float16, pf);
  pf = *pf_ptr;
  pf_ptr += 2 * BATCH * 512;

  // 32 h values (f16) for this thread's K-chunk: 4x ds_read_b128
  const uint4* hv = reinterpret_cast<const uint4*>(&hbuf[cur][cx.ks * 40]);
  const uint4 ua = hv[0];
  const uint4 ub = hv[1];
  half2v hp[16];
  hp[0] = u2h(ua.x); hp[1] = u2h(ua.y); hp[2] = u2h(ua.z); hp[3] = u2h(ua.w);
  hp[4] = u2h(ub.x); hp[5] = u2h(ub.y); hp[6] = u2h(ub.z); hp[7] = u2h(ub.w);
  const uint4 uc = hv[2];
  const uint4 ud = hv[3];
  hp[8]  = u2h(uc.x); hp[9]  = u2h(uc.y); hp[10] = u2h(uc.z); hp[11] = u2h(uc.w);
  hp[12] = u2h(ud.x); hp[13] = u2h(ud.y); hp[14] = u2h(ud.z); hp[15] = u2h(ud.w);

  float ag[4];
#pragma unroll
  for (int g = 0; g < 4; g++) {
    half2v A0 = {0, 0}, A1 = {0, 0}, A2 = {0, 0}, A3 = {0, 0};
#pragma unroll
    for (int j = 0; j < 4; j++) {
      A0 = pkfma(wh[g][4 * j + 0], hp[4 * j + 0], A0);
      A1 = pkfma(wh[g][4 * j + 1], hp[4 * j + 1], A1);
      A2 = pkfma(wh[g][4 * j + 2], hp[4 * j + 2], A2);
      A3 = pkfma(wh[g][4 * j + 3], hp[4 * j + 3], A3);
    }
    const half2v B0 = A0 + A1;          // v_pk_add_f16
    const half2v B1 = A2 + A3;
    ag[g] = ((float)B0[0] + (float)B0[1]) + ((float)B1[0] + (float)B1[1]);
  }
  const float a0 = ag[0], a1 = ag[1], a2 = ag[2], a3 = ag[3];

  // quad reduce-scatter via DPP: lane ks ends with the full sum of gate ks
  const bool q0 = (cx.ks & 1) != 0, q1 = (cx.ks & 2) != 0;
  float s0 = q0 ? a0 : a1;
  float s1 = q0 ? a2 : a3;
  float r0 = qperm<QP_XOR1>(s0);
  float r1 = qperm<QP_XOR1>(s1);
  float kA = (q0 ? a1 : a0) + r0;
  float kB = (q0 ? a3 : a2) + r1;
  float s2 = q1 ? kA : kB;
  float r2 = qperm<QP_XOR2>(s2);
  float sum = (q1 ? kB : kA) + r2 + xpv;

  // ONE activation per lane: y = am * sigmoid(sc*sum) + ab
  float y = cx.am * sigmoid_fast(cx.sc * sum) + cx.ab;

  // all-gather activated gates across the quad via DPP broadcasts
  float gi = qperm<QP_B0>(y);
  float gf = qperm<QP_B1>(y);
  float gg = qperm<QP_B2>(y);
  float go = qperm<QP_B3>(y);

  c = gf * c + gi * gg;
  float th = 2.f * sigmoid_fast(2.f * c) - 1.f;
  float h = go * th;

  if (cx.writer) {
    const _Float16 h16 = (_Float16)h;
    hbuf[cur ^ 1][cx.hidx] = h16;
    *hout_ptr = __builtin_bit_cast(unsigned short, h16);
  }
  hout_ptr += BATCH * 128;

  __syncthreads();
}

__global__ __launch_bounds__(512)
__attribute__((amdgpu_waves_per_eu(2, 2)))
void lstm_rec2(
    const float* __restrict__ Whh,          // [512][128] f32
    const unsigned short* __restrict__ xp,  // [T*B][512] f16 gate-interleaved
    unsigned short* __restrict__ hout)      // [T*B][128] f16
{
  const int b = blockIdx.x;
  const int tid = threadIdx.x;
  const int l = tid & 63;
  const int w = tid >> 6;
  const int rr = l >> 2;
  const int ks = l & 3;
  const int r = w * 16 + rr;

  __shared__ __align__(16) _Float16 hbuf[2][160];  // 4 chunks x 40 halves (80B stride)

  // Whh rows for this thread's 4 gates, chunk ks*32..+32, as f16 pairs (64 VGPR)
  half2v wh[4][16];
#pragma unroll
  for (int g = 0; g < 4; g++) {
    const float4* p = reinterpret_cast<const float4*>(
        Whh + ((size_t)(g * 128 + r)) * 128 + ks * 32);
#pragma unroll
    for (int k = 0; k < 8; k++) {
      float4 f = p[k];
      half2v lo; lo[0] = (_Float16)f.x; lo[1] = (_Float16)f.y;
      half2v hi; hi[0] = (_Float16)f.z; hi[1] = (_Float16)f.w;
      wh[g][2 * k] = lo;
      wh[g][2 * k + 1] = hi;
    }
  }

  StepCtx cx;
  cx.ks = ks; cx.r = r;
  cx.hidx = (r >> 5) * 40 + (r & 31);
  cx.sc = (ks == 2) ? 2.f : 1.f;
  cx.am = (ks == 2) ? 2.f : 1.f;
  cx.ab = (ks == 2) ? -1.f : 0.f;
  cx.writer = (ks == 0);

  if (tid < 160) { hbuf[0][tid] = (_Float16)0.f; }

  const unsigned short* xpb = xp + (size_t)b * 512 + tid;  // tid == r*4+ks
  unsigned short pfa = xpb[0];
  unsigned short pfb = xpb[(size_t)1 * (BATCH * 512)];
  const unsigned short* pA = xpb + (size_t)2 * (BATCH * 512);
  const unsigned short* pB = xpb + (size_t)3 * (BATCH * 512);
  unsigned short* houtp = hout + (size_t)b * 128 + r;
  float c = 0.f;
  __syncthreads();

#pragma unroll 1
  for (int t = 0; t < SEQ_T; t += 2) {
    lstm_step(0, cx, wh, hbuf, pfa, pA, c, houtp);
    lstm_step(1, cx, wh, hbuf, pfb, pB, c, houtp);
  }
}

// ---------------------------------------------------------------------------
// Final linear: out[tb] = h1[tb]·wlin + blin  (R3-proven)
// ---------------------------------------------------------------------------
__global__ __launch_bounds__(256) void final_lin(
    const unsigned short* __restrict__ h1,  // [T*B][128] f16
    const float* __restrict__ Wlin, const float* __restrict__ blin,
    float* __restrict__ out)
{
  const size_t tb = (size_t)blockIdx.x * 256 + threadIdx.x;
  half2v wl[64];
  const float2* p = reinterpret_cast<const float2*>(Wlin);
#pragma unroll
  for (int k = 0; k < 64; k++) {
    float2 f = p[k];
    half2v v; v[0] = (_Float16)f.x; v[1] = (_Float16)f.y;
    wl[k] = v;
  }
  const uint4* hv = reinterpret_cast<const uint4*>(h1 + tb * 128);
  float a0 = 0.f, a1 = 0.f, a2 = 0.f, a3 = 0.f;
#pragma unroll
  for (int i = 0; i < 16; i++) {
    const uint4 u = hv[i];
    a0 = fdot2f(wl[4 * i + 0], u2h(u.x), a0);
    a1 = fdot2f(wl[4 * i + 1], u2h(u.y), a1);
    a2 = fdot2f(wl[4 * i + 2], u2h(u.z), a2);
    a3 = fdot2f(wl[4 * i + 3], u2h(u.w), a3);
  }
  out[tb] = (a0 + a1) + (a2 + a3) + blin[0];
}

extern "C" void kernel_launch(void* const* d_in, const int* in_sizes, int n_in,
                              void* d_out, int out_size, void* d_ws, size_t ws_size,
                              hipStream_t stream) {
  (void)in_sizes; (void)n_in; (void)out_size; (void)ws_size;

  const float* data = (const float*)d_in[0];
  const float* Wih0 = (const float*)d_in[1];
  const float* Whh0 = (const float*)d_in[2];
  const float* bih0 = (const float*)d_in[3];
  const float* bhh0 = (const float*)d_in[4];
  const float* Wih1 = (const float*)d_in[5];
  const float* Whh1 = (const float*)d_in[6];
  const float* bih1 = (const float*)d_in[7];
  const float* bhh1 = (const float*)d_in[8];
  const float* Wlin = (const float*)d_in[9];
  const float* blin = (const float*)d_in[10];

  // ws layout: xp 128 MiB | h0 32 MiB | h1 32 MiB
  unsigned char* ws = (unsigned char*)d_ws;
  unsigned short* xpb = (unsigned short*)ws;
  unsigned short* h0 = (unsigned short*)(ws + (size_t)128 * 1024 * 1024);
  unsigned short* h1 = (unsigned short*)(ws + (size_t)160 * 1024 * 1024);

  const int M = SEQ_T * BATCH;
  const int gemm_blocks = M / 64;

  xproj_gemm<64, true><<<dim3(gemm_blocks), dim3(512), 0, stream>>>(
      data, Wih0, bih0, bhh0, xpb);
  lstm_rec2<<<dim3(BATCH), dim3(512), 0, stream>>>(Whh0, xpb, h0);
  xproj_gemm<128, false><<<dim3(gemm_blocks), dim3(512), 0, stream>>>(
      h0, Wih1, bih1, bhh1, xpb);
  lstm_rec2<<<dim3(BATCH), dim3(512), 0, stream>>>(Whh1, xpb, h1);
  final_lin<<<dim3(M / 256), dim3(256), 0, stream>>>(h1, Wlin, blin, (float*)d_out);
}

// Round 16
// 3161.056 us; speedup vs baseline: 1.2060x; 1.0149x over previous
//
#include <hip/hip_runtime.h>

#define SEQ_T 2048
#define BATCH 64

typedef _Float16 half2v __attribute__((ext_vector_type(2)));

#if defined(__has_builtin)
#  if __has_builtin(__builtin_amdgcn_fdot2)
#    define HAVE_FDOT2 1
#  endif
#endif

// f16-pair dot with f32 accumulate — builtin or exact-f32 fallback.
// NOTE: inline-asm v_dot2_f32_f16 correlated with ~0.1 absmax (R4/R5) — banned.
// NOTE: inline-asm v_fma_mix_f32 was a regression (R13/R14, likely half-rate) — banned.
__device__ __forceinline__ float fdot2f(half2v a, half2v b, float c) {
#ifdef HAVE_FDOT2
  return __builtin_amdgcn_fdot2(a, b, c, false);
#else
  return c + (float)a[0] * (float)b[0] + (float)a[1] * (float)b[1];
#endif
}

// Forced VOP3P packed f16 ops (R15 showed clang scalarizes half2 math).
// Semantics: independent per-slot IEEE f16 FMA/add — identical to the
// scalarized form R15 validated (absmax 0.001953).
__device__ __forceinline__ half2v pkfma_asm(half2v a, half2v b, half2v c) {
  asm("v_pk_fma_f16 %0, %1, %2, %0" : "+v"(c) : "v"(a), "v"(b));
  return c;
}
__device__ __forceinline__ half2v pkadd_asm(half2v a, half2v b) {
  half2v r;
  asm("v_pk_add_f16 %0, %1, %2" : "=v"(r) : "v"(a), "v"(b));
  return r;
}

__device__ __forceinline__ unsigned int h2u(half2v v) { return __builtin_bit_cast(unsigned int, v); }
__device__ __forceinline__ half2v u2h(unsigned int u) { return __builtin_bit_cast(half2v, u); }

// Within-quad lane permute on the VALU (DPP quad_perm) — no LDS pipe.
template <int CTRL>
__device__ __forceinline__ float qperm(float x) {
  int xi = __builtin_bit_cast(int, x);
  int ri = __builtin_amdgcn_update_dpp(xi, xi, CTRL, 0xF, 0xF, true);
  return __builtin_bit_cast(float, ri);
}
#define QP_XOR1 0xB1  // [1,0,3,2]
#define QP_XOR2 0x4E  // [2,3,0,1]
#define QP_B0   0x00
#define QP_B1   0x55
#define QP_B2   0xAA
#define QP_B3   0xFF

// ---------------------------------------------------------------------------
// xproj GEMM (R2/R3-proven, unchanged): xp[tb][r*4+g] gate-interleaved f16.
// ---------------------------------------------------------------------------
template <int K, bool IN_F32>
__global__ __launch_bounds__(512) void xproj_gemm(
    const void* __restrict__ Xv,            // [M][K] f32 or f16
    const float* __restrict__ W,            // [512][K] f32
    const float* __restrict__ bih, const float* __restrict__ bhh,
    unsigned short* __restrict__ xp)        // [M][512] f16, gate-interleaved
{
  constexpr int MT = 64;
  const int g = threadIdx.x;
  const size_t m0 = (size_t)blockIdx.x * MT;

  __shared__ __align__(16) _Float16 xs[MT * K];

  if constexpr (IN_F32) {
    constexpr int PER = MT * K / 512;
    const float* Xf = (const float*)Xv + m0 * K + (size_t)g * PER;
    _Float16* dst = xs + g * PER;
#pragma unroll
    for (int i = 0; i < PER; i += 4) {
      float4 v = *reinterpret_cast<const float4*>(Xf + i);
      half2v h01; h01[0] = (_Float16)v.x; h01[1] = (_Float16)v.y;
      half2v h23; h23[0] = (_Float16)v.z; h23[1] = (_Float16)v.w;
      uint2 u; u.x = h2u(h01); u.y = h2u(h23);
      *reinterpret_cast<uint2*>(dst + i) = u;
    }
  } else {
    constexpr int PER = MT * K / 512;
    const unsigned short* Xh = (const unsigned short*)Xv + m0 * K + (size_t)g * PER;
#pragma unroll
    for (int i = 0; i < PER / 8; i++)
      reinterpret_cast<uint4*>(xs + g * PER)[i] = reinterpret_cast<const uint4*>(Xh)[i];
  }

  half2v wr[K / 2];
  {
    const float2* p = reinterpret_cast<const float2*>(W + (size_t)g * K);
#pragma unroll
    for (int k = 0; k < K / 2; k++) {
      float2 f = p[k];
      half2v v; v[0] = (_Float16)f.x; v[1] = (_Float16)f.y;
      wr[k] = v;
    }
  }
  const float bias = bih[g] + bhh[g];
  const int out_off = (g & 127) * 4 + (g >> 7);
  __syncthreads();

#pragma unroll 1
  for (int tb = 0; tb < MT; tb++) {
    const uint4* xv = reinterpret_cast<const uint4*>(xs + tb * K);
    float a0 = bias, a1 = 0.f, a2 = 0.f, a3 = 0.f;
#pragma unroll
    for (int i = 0; i < K / 8; i++) {
      const uint4 u = xv[i];
      a0 = fdot2f(wr[4 * i + 0], u2h(u.x), a0);
      a1 = fdot2f(wr[4 * i + 1], u2h(u.y), a1);
      a2 = fdot2f(wr[4 * i + 2], u2h(u.z), a2);
      a3 = fdot2f(wr[4 * i + 3], u2h(u.w), a3);
    }
    const float s = (a0 + a1) + (a2 + a3);
    xp[(m0 + tb) * 512 + out_off] = __builtin_bit_cast(unsigned short, (_Float16)s);
  }
}

// ---------------------------------------------------------------------------
// Recurrence R16 = R15 with the packed-f16 dot phase FORCED via inline asm
// (v_pk_fma_f16 / v_pk_add_f16), round-robined across 16 independent
// accumulator chains so the 4-cyc FMA latency is hidden. All other structure
// (f16 weights resident, f16 skewed hbuf, DPP quad reduce, activation,
// 2-deep xp prefetch) is R15/R9-verbatim.
// thread = (row r = wave*16 + (l>>2), K-split ks = l&3).
// ---------------------------------------------------------------------------
struct StepCtx {
  int ks, r, hidx;
  float sc, am, ab;
  bool writer;
};

__device__ __forceinline__ float sigmoid_fast(float x) {
  return 1.f / (1.f + __expf(-x));
}

__device__ __forceinline__ void lstm_step(
    int cur, const StepCtx& cx,
    const half2v (&wh)[4][16], _Float16 (&hbuf)[2][160],
    unsigned short& pf, const unsigned short*& pf_ptr,
    float& c, unsigned short*& hout_ptr)
{
  // consume 2-steps-ago prefetch; immediately re-issue 2 ahead
  const float xpv = (float)__builtin_bit_cast(_Float16, pf);
  pf = *pf_ptr;
  pf_ptr += 2 * BATCH * 512;

  // 32 h values (f16) for this thread's K-chunk: 4x ds_read_b128
  const uint4* hvp = reinterpret_cast<const uint4*>(&hbuf[cur][cx.ks * 40]);
  const uint4 ua = hvp[0];
  const uint4 ub = hvp[1];
  const uint4 uc = hvp[2];
  const uint4 ud = hvp[3];
  half2v hh[16];
  hh[0]  = u2h(ua.x); hh[1]  = u2h(ua.y); hh[2]  = u2h(ua.z); hh[3]  = u2h(ua.w);
  hh[4]  = u2h(ub.x); hh[5]  = u2h(ub.y); hh[6]  = u2h(ub.z); hh[7]  = u2h(ub.w);
  hh[8]  = u2h(uc.x); hh[9]  = u2h(uc.y); hh[10] = u2h(uc.z); hh[11] = u2h(uc.w);
  hh[12] = u2h(ud.x); hh[13] = u2h(ud.y); hh[14] = u2h(ud.z); hh[15] = u2h(ud.w);

  // 16 independent accumulator chains (4 per gate), round-robin issue:
  // chain (g, jj&3) touched every 4 instructions.
  half2v acc[4][4];
#pragma unroll
  for (int g = 0; g < 4; g++)
#pragma unroll
    for (int j = 0; j < 4; j++) { half2v z = {0, 0}; acc[g][j] = z; }

#pragma unroll
  for (int jj = 0; jj < 16; jj++) {
    acc[0][jj & 3] = pkfma_asm(wh[0][jj], hh[jj], acc[0][jj & 3]);
    acc[1][jj & 3] = pkfma_asm(wh[1][jj], hh[jj], acc[1][jj & 3]);
    acc[2][jj & 3] = pkfma_asm(wh[2][jj], hh[jj], acc[2][jj & 3]);
    acc[3][jj & 3] = pkfma_asm(wh[3][jj], hh[jj], acc[3][jj & 3]);
  }

  float ag[4];
#pragma unroll
  for (int g = 0; g < 4; g++) {
    const half2v s01 = pkadd_asm(acc[g][0], acc[g][1]);
    const half2v s23 = pkadd_asm(acc[g][2], acc[g][3]);
    const half2v s = pkadd_asm(s01, s23);
    ag[g] = (float)s[0] + (float)s[1];
  }
  const float a0 = ag[0], a1 = ag[1], a2 = ag[2], a3 = ag[3];

  // quad reduce-scatter via DPP: lane ks ends with the full sum of gate ks
  const bool q0 = (cx.ks & 1) != 0, q1 = (cx.ks & 2) != 0;
  float s0 = q0 ? a0 : a1;
  float s1 = q0 ? a2 : a3;
  float r0 = qperm<QP_XOR1>(s0);
  float r1 = qperm<QP_XOR1>(s1);
  float kA = (q0 ? a1 : a0) + r0;
  float kB = (q0 ? a3 : a2) + r1;
  float s2 = q1 ? kA : kB;
  float r2 = qperm<QP_XOR2>(s2);
  float sum = (q1 ? kB : kA) + r2 + xpv;

  // ONE activation per lane: y = am * sigmoid(sc*sum) + ab
  float y = cx.am * sigmoid_fast(cx.sc * sum) + cx.ab;

  // all-gather activated gates across the quad via DPP broadcasts
  float gi = qperm<QP_B0>(y);
  float gf = qperm<QP_B1>(y);
  float gg = qperm<QP_B2>(y);
  float go = qperm<QP_B3>(y);

  c = gf * c + gi * gg;
  float th = 2.f * sigmoid_fast(2.f * c) - 1.f;
  float h = go * th;

  if (cx.writer) {
    const _Float16 h16 = (_Float16)h;
    hbuf[cur ^ 1][cx.hidx] = h16;
    *hout_ptr = __builtin_bit_cast(unsigned short, h16);
  }
  hout_ptr += BATCH * 128;

  __syncthreads();
}

__global__ __launch_bounds__(512)
__attribute__((amdgpu_waves_per_eu(2, 2)))
void lstm_rec2(
    const float* __restrict__ Whh,          // [512][128] f32
    const unsigned short* __restrict__ xp,  // [T*B][512] f16 gate-interleaved
    unsigned short* __restrict__ hout)      // [T*B][128] f16
{
  const int b = blockIdx.x;
  const int tid = threadIdx.x;
  const int l = tid & 63;
  const int w = tid >> 6;
  const int rr = l >> 2;
  const int ks = l & 3;
  const int r = w * 16 + rr;

  __shared__ __align__(16) _Float16 hbuf[2][160];  // 4 chunks x 40 halves (80B stride)

  // Whh rows for this thread's 4 gates, chunk ks*32..+32, as f16 pairs (64 VGPR)
  half2v wh[4][16];
#pragma unroll
  for (int g = 0; g < 4; g++) {
    const float4* p = reinterpret_cast<const float4*>(
        Whh + ((size_t)(g * 128 + r)) * 128 + ks * 32);
#pragma unroll
    for (int k = 0; k < 8; k++) {
      float4 f = p[k];
      half2v lo; lo[0] = (_Float16)f.x; lo[1] = (_Float16)f.y;
      half2v hi; hi[0] = (_Float16)f.z; hi[1] = (_Float16)f.w;
      wh[g][2 * k] = lo;
      wh[g][2 * k + 1] = hi;
    }
  }

  StepCtx cx;
  cx.ks = ks; cx.r = r;
  cx.hidx = (r >> 5) * 40 + (r & 31);
  cx.sc = (ks == 2) ? 2.f : 1.f;
  cx.am = (ks == 2) ? 2.f : 1.f;
  cx.ab = (ks == 2) ? -1.f : 0.f;
  cx.writer = (ks == 0);

  if (tid < 160) { hbuf[0][tid] = (_Float16)0.f; }

  const unsigned short* xpb = xp + (size_t)b * 512 + tid;  // tid == r*4+ks
  unsigned short pfa = xpb[0];
  unsigned short pfb = xpb[(size_t)1 * (BATCH * 512)];
  const unsigned short* pA = xpb + (size_t)2 * (BATCH * 512);
  const unsigned short* pB = xpb + (size_t)3 * (BATCH * 512);
  unsigned short* houtp = hout + (size_t)b * 128 + r;
  float c = 0.f;
  __syncthreads();

#pragma unroll 1
  for (int t = 0; t < SEQ_T; t += 2) {
    lstm_step(0, cx, wh, hbuf, pfa, pA, c, houtp);
    lstm_step(1, cx, wh, hbuf, pfb, pB, c, houtp);
  }
}

// ---------------------------------------------------------------------------
// Final linear: out[tb] = h1[tb]·wlin + blin  (R3-proven)
// ---------------------------------------------------------------------------
__global__ __launch_bounds__(256) void final_lin(
    const unsigned short* __restrict__ h1,  // [T*B][128] f16
    const float* __restrict__ Wlin, const float* __restrict__ blin,
    float* __restrict__ out)
{
  const size_t tb = (size_t)blockIdx.x * 256 + threadIdx.x;
  half2v wl[64];
  const float2* p = reinterpret_cast<const float2*>(Wlin);
#pragma unroll
  for (int k = 0; k < 64; k++) {
    float2 f = p[k];
    half2v v; v[0] = (_Float16)f.x; v[1] = (_Float16)f.y;
    wl[k] = v;
  }
  const uint4* hv = reinterpret_cast<const uint4*>(h1 + tb * 128);
  float a0 = 0.f, a1 = 0.f, a2 = 0.f, a3 = 0.f;
#pragma unroll
  for (int i = 0; i < 16; i++) {
    const uint4 u = hv[i];
    a0 = fdot2f(wl[4 * i + 0], u2h(u.x), a0);
    a1 = fdot2f(wl[4 * i + 1], u2h(u.y), a1);
    a2 = fdot2f(wl[4 * i + 2], u2h(u.z), a2);
    a3 = fdot2f(wl[4 * i + 3], u2h(u.w), a3);
  }
  out[tb] = (a0 + a1) + (a2 + a3) + blin[0];
}

extern "C" void kernel_launch(void* const* d_in, const int* in_sizes, int n_in,
                              void* d_out, int out_size, void* d_ws, size_t ws_size,
                              hipStream_t stream) {
  (void)in_sizes; (void)n_in; (void)out_size; (void)ws_size;

  const float* data = (const float*)d_in[0];
  const float* Wih0 = (const float*)d_in[1];
  const float* Whh0 = (const float*)d_in[2];
  const float* bih0 = (const float*)d_in[3];
  const float* bhh0 = (const float*)d_in[4];
  const float* Wih1 = (const float*)d_in[5];
  const float* Whh1 = (const float*)d_in[6];
  const float* bih1 = (const float*)d_in[7];
  const float* bhh1 = (const float*)d_in[8];
  const float* Wlin = (const float*)d_in[9];
  const float* blin = (const float*)d_in[10];

  // ws layout: xp 128 MiB | h0 32 MiB | h1 32 MiB
  unsigned char* ws = (unsigned char*)d_ws;
  unsigned short* xpb = (unsigned short*)ws;
  unsigned short* h0 = (unsigned short*)(ws + (size_t)128 * 1024 * 1024);
  unsigned short* h1 = (unsigned short*)(ws + (size_t)160 * 1024 * 1024);

  const int M = SEQ_T * BATCH;
  const int gemm_blocks = M / 64;

  xproj_gemm<64, true><<<dim3(gemm_blocks), dim3(512), 0, stream>>>(
      data, Wih0, bih0, bhh0, xpb);
  lstm_rec2<<<dim3(BATCH), dim3(512), 0, stream>>>(Whh0, xpb, h0);
  xproj_gemm<128, false><<<dim3(gemm_blocks), dim3(512), 0, stream>>>(
      h0, Wih1, bih1, bhh1, xpb);
  lstm_rec2<<<dim3(BATCH), dim3(512), 0, stream>>>(Whh1, xpb, h1);
  final_lin<<<dim3(M / 256), dim3(256), 0, stream>>>(h1, Wlin, blin, (float*)d_out);
}